// Round 10
// baseline (151.297 us; speedup 1.0000x reference)
//
#include <hip/hip_runtime.h>
#include <math.h>

// Problem constants
#define R_ 5
#define NN 68        // N_NODES == LATENT
#define KK 32        // neighbors per node
#define NL 3         // GCN layers
#define LAT 68
#define NSL 17               // nodes per wave slice (4 waves x 17 = 68)
#define ROWQ (NN / 4)        // 17 float4 per node row
#define NF4 ((NN * NN) / 4)  // 1156 float4 per output row
#define BBK2 16              // batches per K2 block
#define LSTR 344             // LDS row stride (floats) for K2, 16B-aligned

// ---------------- P1: densify GCN weights ----------------
// W'[m][n] = sum_{k: adj[n,k]==m} gw[n,k]  (exact rewrite of the gather)
__global__ __launch_bounds__(128) void densify_k(
    const int* __restrict__ adj, const float* __restrict__ gw,
    float* __restrict__ wd) {
  const int rl = blockIdx.x;  // r*NL + l in 0..14
  const int t = threadIdx.x;
  __shared__ float col[NN][NN + 4];
  for (int i = t; i < NN * (NN + 4); i += 128) (&col[0][0])[i] = 0.0f;
  __syncthreads();
  if (t < NN) {
    const int n = t;  // thread owns column n -> no races
    const int* ar = adj + n * KK;
    const float* wr = gw + ((size_t)rl * NN + n) * KK;
    for (int k = 0; k < KK; ++k) col[ar[k]][n] += wr[k];
  }
  __syncthreads();
  float* wout = wd + (size_t)rl * NN * NN;  // [m][n], n contiguous
  for (int i = t; i < NN * NN; i += 128) {
    const int m = i / NN, n = i - m * NN;
    wout[i] = col[m][n];
  }
}

// ---------------- P2: transpose z -> zT[l][b] ----------------
__global__ __launch_bounds__(256) void ztr_k(const float* __restrict__ z,
                                             float* __restrict__ zT, int B) {
  const int t = threadIdx.x;
  const int b0 = blockIdx.x * 64;
  __shared__ float zls[64][LAT + 1];  // +1: stride 69 -> conflict-free both ways
  for (int idx = t; idx < 64 * ROWQ; idx += 256) {
    const int row = idx / ROWQ, q = idx - row * ROWQ;
    const float4 v =
        *reinterpret_cast<const float4*>(z + (size_t)(b0 + row) * LAT + 4 * q);
    zls[row][4 * q + 0] = v.x;
    zls[row][4 * q + 1] = v.y;
    zls[row][4 * q + 2] = v.z;
    zls[row][4 * q + 3] = v.w;
  }
  __syncthreads();
  for (int idx = t; idx < LAT * 64; idx += 256) {
    const int l = idx >> 6, bb = idx & 63;
    zT[(size_t)l * B + b0 + bb] = zls[bb][l];
  }
}

// ---------------- K1: GEMM-chain, 4 waves x 17 nodes, 2 batches/lane -------
// Block = (r, 128-batch group), 256 threads. lane = batch pair (lane,
// lane+64). Wave w owns node slice [17w,17w+17), base wave-uniform via
// readfirstlane -> weight/bias addresses scalarize to s_load. 2 batches/lane
// halves the scalar-stream + ds_read cost per batch vs v6 (the latency item)
// while doubling per-iter VALU (34->68 cyc) to keep it covered at 2.5
// waves/SIMD. 640 blocks.
__global__ __launch_bounds__(256) void chain_k(
    const float* __restrict__ zT, const float* __restrict__ fc_w,
    const float* __restrict__ fc_b, const float* __restrict__ wd,
    const float* __restrict__ gb, float* __restrict__ X, int B, int ng) {
  const int t = threadIdx.x;
  const int lane = t & 63;
  const int w = __builtin_amdgcn_readfirstlane(t >> 6);
  const int n0 = w * NSL;  // first node of this wave's slice (wave-uniform)
  const int r = blockIdx.x / ng;
  const int b0 = (blockIdx.x - r * ng) * 128;

  __shared__ float xs[NN][128];  // 34.8 KB; z, then x, per stage

  for (int idx = t; idx < NN * 128; idx += 256) {
    const int m = idx >> 7;
    xs[m][idx & 127] = zT[(size_t)m * B + b0 + (idx & 127)];
  }
  __syncthreads();

  float acc0[NSL], acc1[NSL];

#pragma unroll 1
  for (int stage = 0; stage < 1 + NL; ++stage) {
    const float* wb = (stage == 0) ? fc_w + (size_t)r * LAT * NN
                                   : wd + (size_t)(r * NL + stage - 1) * NN * NN;
    const float* bias = (stage == 0) ? fc_b + r * NN
                                     : gb + (size_t)(r * NL + stage - 1) * NN;
#pragma unroll
    for (int j = 0; j < NSL; ++j) {  // uniform -> s_load
      acc0[j] = bias[n0 + j];
      acc1[j] = acc0[j];
    }

#pragma unroll 2
    for (int m = 0; m < NN; ++m) {
      const float xm0 = xs[m][lane];        // stride-64, conflict-free
      const float xm1 = xs[m][lane + 64];
      const float* wr = wb + m * NN + n0;   // wave-uniform -> s_load chunk
#pragma unroll
      for (int j = 0; j < NSL; ++j) {
        const float wv = wr[j];
        acc0[j] = fmaf(xm0, wv, acc0[j]);
        acc1[j] = fmaf(xm1, wv, acc1[j]);
      }
    }
    if (stage > 0) {
#pragma unroll
      for (int j = 0; j < NSL; ++j) {
        acc0[j] = 1.0f / (1.0f + __expf(-acc0[j]));
        acc1[j] = 1.0f / (1.0f + __expf(-acc1[j]));
      }
    }
    if (stage < NL) {
      __syncthreads();  // everyone done READING xs for this stage
#pragma unroll
      for (int j = 0; j < NSL; ++j) {
        xs[n0 + j][lane] = acc0[j];
        xs[n0 + j][lane + 64] = acc1[j];
      }
      __syncthreads();
    }
  }

  // ---- final X -> ws, layout [r*68+n][b]: coalesced 256B rows ----
  float* Xb = X + ((size_t)r * NN + n0) * B + b0;
#pragma unroll
  for (int j = 0; j < NSL; ++j) {
    Xb[(size_t)j * B + lane] = acc0[j];
    Xb[(size_t)j * B + 64 + lane] = acc1[j];
  }
}

// ---------------- K2: outer product, reg-tiled, direct PLAIN stores --------
// v8's register reuse (xj preloaded once, xi one broadcast b128 per r per
// 4-row group) with plain stores: L2 write-merges the 272B-row partial lines
// across i-iterations (v8's +24% WRITE_SIZE came from nt-stores bypassing
// that merge). Edge f4-column 16 fused into the k-loop on c==0 lanes.
__global__ __launch_bounds__(256) void outer_k(const float* __restrict__ X,
                                               float* __restrict__ out, int B) {
  const int t = threadIdx.x;
  const int b0 = blockIdx.x * BBK2;
  __shared__ float xls[BBK2 * LSTR];  // 22.0 KB

  // stage X[rn][b0..b0+15] -> xls[bb][rn]; reads are exact 64B lines
  for (int idx = t; idx < R_ * NN * BBK2; idx += 256) {
    const int rn = idx >> 4, bb = idx & (BBK2 - 1);
    xls[bb * LSTR + rn] = X[(size_t)rn * B + b0 + bb];
  }
  __syncthreads();

  const int lane = t & 63;
  const int wv = t >> 6;
  const int bb = wv * 4 + (lane >> 4);  // 0..15
  const int c = lane & 15;              // f4-col 0..15; lane c==0 also col 16
  const float* xb = &xls[bb * LSTR];

  float4 xj[R_], xj16[R_];
#pragma unroll
  for (int r = 0; r < R_; ++r)
    xj[r] = *reinterpret_cast<const float4*>(xb + r * NN + 4 * c);
#pragma unroll
  for (int r = 0; r < R_; ++r)
    xj16[r] = *reinterpret_cast<const float4*>(xb + r * NN + 64);

  float4* obase = reinterpret_cast<float4*>(out) + (size_t)(b0 + bb) * NF4;
#pragma unroll 2
  for (int g = 0; g < 17; ++g) {  // rows i = 4g..4g+3
    float4 xi[R_];
#pragma unroll
    for (int r = 0; r < R_; ++r)
      xi[r] = *reinterpret_cast<const float4*>(xb + r * NN + 4 * g);  // bcast
#pragma unroll
    for (int k = 0; k < 4; ++k) {
      float4 a = make_float4(0.f, 0.f, 0.f, 0.f);
#pragma unroll
      for (int r = 0; r < R_; ++r) {
        const float s = reinterpret_cast<const float*>(&xi[r])[k];  // static k
        a.x = fmaf(s, xj[r].x, a.x);
        a.y = fmaf(s, xj[r].y, a.y);
        a.z = fmaf(s, xj[r].z, a.z);
        a.w = fmaf(s, xj[r].w, a.w);
      }
      obase[(size_t)(4 * g + k) * ROWQ + c] = a;
      if (c == 0) {  // edge f4-column 16 (cols 64..67)
        float4 e = make_float4(0.f, 0.f, 0.f, 0.f);
#pragma unroll
        for (int r = 0; r < R_; ++r) {
          const float s = reinterpret_cast<const float*>(&xi[r])[k];
          e.x = fmaf(s, xj16[r].x, e.x);
          e.y = fmaf(s, xj16[r].y, e.y);
          e.z = fmaf(s, xj16[r].z, e.z);
          e.w = fmaf(s, xj16[r].w, e.w);
        }
        obase[(size_t)(4 * g + k) * ROWQ + 16] = e;
      }
    }
  }
}

extern "C" void kernel_launch(void* const* d_in, const int* in_sizes, int n_in,
                              void* d_out, int out_size, void* d_ws, size_t ws_size,
                              hipStream_t stream) {
  const float* z    = (const float*)d_in[0];  // (16384, 68)
  const int*   adj  = (const int*)  d_in[1];  // (68, 32)
  const float* fc_w = (const float*)d_in[2];  // (5, 68, 68)
  const float* fc_b = (const float*)d_in[3];  // (5, 68)
  const float* gw   = (const float*)d_in[4];  // (5, 3, 68, 32)
  const float* gb   = (const float*)d_in[5];  // (5, 3, 68)
  float* out = (float*)d_out;                 // (16384, 4624)

  const int B = in_sizes[0] / LAT;            // 16384
  // ws layout (f32): wd[15*68*68] | zT[68*B] | X[340*B]  (~27.1 MB total)
  float* wd = (float*)d_ws;
  float* zT = wd + R_ * NL * NN * NN;
  float* X  = zT + (size_t)LAT * B;

  const int ng = B / 128;                     // 128 batch-groups (chain)

  densify_k<<<R_ * NL, 128, 0, stream>>>(adj, gw, wd);
  ztr_k<<<B / 64, 256, 0, stream>>>(z, zT, B);
  chain_k<<<R_ * ng, 256, 0, stream>>>(zT, fc_w, fc_b, wd, gb, X, B, ng);
  outer_k<<<B / BBK2, 256, 0, stream>>>(X, out, B);
}

// Round 11
// 143.912 us; speedup vs baseline: 1.0513x; 1.0513x over previous
//
#include <hip/hip_runtime.h>
#include <math.h>

// Problem constants
#define R_ 5
#define NN 68        // N_NODES == LATENT
#define KK 32        // neighbors per node
#define NL 3         // GCN layers
#define LAT 68
#define NSL 17               // nodes per wave slice (4 waves x 17 = 68)
#define ROWQ (NN / 4)        // 17 float4 per node row
#define NF4 ((NN * NN) / 4)  // 1156 float4 per output row
#define BBK2 16              // batches per K2 block
#define LSTR (R_ * NN)       // 340: f4-aligned (1360B), bank stride 20 -> 2-way max

// ---------------- P1: densify GCN weights ----------------
// W'[m][n] = sum_{k: adj[n,k]==m} gw[n,k]  (exact rewrite of the gather)
__global__ __launch_bounds__(128) void densify_k(
    const int* __restrict__ adj, const float* __restrict__ gw,
    float* __restrict__ wd) {
  const int rl = blockIdx.x;  // r*NL + l in 0..14
  const int t = threadIdx.x;
  __shared__ float col[NN][NN + 4];
  for (int i = t; i < NN * (NN + 4); i += 128) (&col[0][0])[i] = 0.0f;
  __syncthreads();
  if (t < NN) {
    const int n = t;  // thread owns column n -> no races
    const int* ar = adj + n * KK;
    const float* wr = gw + ((size_t)rl * NN + n) * KK;
    for (int k = 0; k < KK; ++k) col[ar[k]][n] += wr[k];
  }
  __syncthreads();
  float* wout = wd + (size_t)rl * NN * NN;  // [m][n], n contiguous
  for (int i = t; i < NN * NN; i += 128) {
    const int m = i / NN, n = i - m * NN;
    wout[i] = col[m][n];
  }
}

// ---------------- P2: transpose z -> zT[l][b] ----------------
__global__ __launch_bounds__(256) void ztr_k(const float* __restrict__ z,
                                             float* __restrict__ zT, int B) {
  const int t = threadIdx.x;
  const int b0 = blockIdx.x * 64;
  __shared__ float zls[64][LAT + 1];  // +1: stride 69 -> conflict-free both ways
  for (int idx = t; idx < 64 * ROWQ; idx += 256) {
    const int row = idx / ROWQ, q = idx - row * ROWQ;
    const float4 v =
        *reinterpret_cast<const float4*>(z + (size_t)(b0 + row) * LAT + 4 * q);
    zls[row][4 * q + 0] = v.x;
    zls[row][4 * q + 1] = v.y;
    zls[row][4 * q + 2] = v.z;
    zls[row][4 * q + 3] = v.w;
  }
  __syncthreads();
  for (int idx = t; idx < LAT * 64; idx += 256) {
    const int l = idx >> 6, bb = idx & 63;
    zT[(size_t)l * B + b0 + bb] = zls[bb][l];
  }
}

// ---------------- K1: GEMM-chain, 4 waves x 17-node slices ----------------
// (v6 verbatim — best measured chain: scalar s_load weight path, 20 waves/CU)
__global__ __launch_bounds__(256) void chain_k(
    const float* __restrict__ zT, const float* __restrict__ fc_w,
    const float* __restrict__ fc_b, const float* __restrict__ wd,
    const float* __restrict__ gb, float* __restrict__ X, int B, int nb) {
  const int t = threadIdx.x;
  const int lane = t & 63;
  const int w = __builtin_amdgcn_readfirstlane(t >> 6);
  const int n0 = w * NSL;  // first node of this wave's slice (wave-uniform)
  const int r = blockIdx.x / nb;
  const int b0 = (blockIdx.x - r * nb) * 64;

  __shared__ float xs[NN][64];  // 17.4 KB; z, then x, per stage

  for (int idx = t; idx < NN * 64; idx += 256) {
    const int m = idx >> 6;
    xs[m][idx & 63] = zT[(size_t)m * B + b0 + (idx & 63)];
  }
  __syncthreads();

  float acc[NSL];

#pragma unroll 1
  for (int stage = 0; stage < 1 + NL; ++stage) {
    const float* wb = (stage == 0) ? fc_w + (size_t)r * LAT * NN
                                   : wd + (size_t)(r * NL + stage - 1) * NN * NN;
    const float* bias = (stage == 0) ? fc_b + r * NN
                                     : gb + (size_t)(r * NL + stage - 1) * NN;
#pragma unroll
    for (int j = 0; j < NSL; ++j) acc[j] = bias[n0 + j];  // uniform -> s_load

#pragma unroll 2
    for (int m = 0; m < NN; ++m) {
      const float xm = xs[m][lane];          // stride-64, conflict-free
      const float* wr = wb + m * NN + n0;    // wave-uniform -> s_load chunk
#pragma unroll
      for (int j = 0; j < NSL; ++j) acc[j] = fmaf(xm, wr[j], acc[j]);
    }
    if (stage > 0) {
#pragma unroll
      for (int j = 0; j < NSL; ++j)
        acc[j] = 1.0f / (1.0f + __expf(-acc[j]));
    }
    if (stage < NL) {
      __syncthreads();
#pragma unroll
      for (int j = 0; j < NSL; ++j) xs[n0 + j][lane] = acc[j];
      __syncthreads();
    }
  }

  float* Xb = X + ((size_t)r * NN + n0) * B + b0 + lane;
#pragma unroll
  for (int j = 0; j < NSL; ++j) Xb[(size_t)j * B] = acc[j];
}

// ---------------- K2: outer product, q-per-lane row stores ----------------
// Thread -> (bb = t/17, q = t%17); 272 active of 320. xj[r] (q-column f4)
// loaded ONCE (5 b128). i-loop: 5 broadcast ds_read_b32 (~29 LDS cyc/wave-
// iter, vs v6's 90) + 20 fmac + 1 f4 store. 17-lane groups write complete
// 272B rows contiguously; consecutive i -> adjacent rows -> L2 assembles
// full lines (keeps v6's clean WRITE_SIZE, drops its LDS serialization).
__global__ __launch_bounds__(320) void outer_k(const float* __restrict__ X,
                                               float* __restrict__ out, int B) {
  const int t = threadIdx.x;
  const int b0 = blockIdx.x * BBK2;
  __shared__ float xls[BBK2 * LSTR];  // 21.8 KB

  // stage X[rn][b0..b0+15] -> xls[bb][rn]; reads are exact 64B lines
  for (int idx = t; idx < R_ * NN * BBK2; idx += 320) {
    const int rn = idx >> 4, bb = idx & (BBK2 - 1);
    xls[bb * LSTR + rn] = X[(size_t)rn * B + b0 + bb];
  }
  __syncthreads();

  if (t < BBK2 * ROWQ) {  // 272 active
    const int bb = t / ROWQ;
    const int q = t - bb * ROWQ;
    const float* xb = &xls[bb * LSTR];

    float4 xj[R_];
#pragma unroll
    for (int r = 0; r < R_; ++r)
      xj[r] = *reinterpret_cast<const float4*>(xb + r * NN + 4 * q);

    float4* obase = reinterpret_cast<float4*>(out) + (size_t)(b0 + bb) * NF4 + q;
#pragma unroll 2
    for (int i = 0; i < NN; ++i) {
      float4 a = make_float4(0.f, 0.f, 0.f, 0.f);
#pragma unroll
      for (int r = 0; r < R_; ++r) {
        const float s = xb[r * NN + i];  // broadcast within 17-lane group
        a.x = fmaf(s, xj[r].x, a.x);
        a.y = fmaf(s, xj[r].y, a.y);
        a.z = fmaf(s, xj[r].z, a.z);
        a.w = fmaf(s, xj[r].w, a.w);
      }
      obase[(size_t)i * ROWQ] = a;  // row i: 17 lanes = full 272B contiguous
    }
  }
}

extern "C" void kernel_launch(void* const* d_in, const int* in_sizes, int n_in,
                              void* d_out, int out_size, void* d_ws, size_t ws_size,
                              hipStream_t stream) {
  const float* z    = (const float*)d_in[0];  // (16384, 68)
  const int*   adj  = (const int*)  d_in[1];  // (68, 32)
  const float* fc_w = (const float*)d_in[2];  // (5, 68, 68)
  const float* fc_b = (const float*)d_in[3];  // (5, 68)
  const float* gw   = (const float*)d_in[4];  // (5, 3, 68, 32)
  const float* gb   = (const float*)d_in[5];  // (5, 3, 68)
  float* out = (float*)d_out;                 // (16384, 4624)

  const int B = in_sizes[0] / LAT;            // 16384
  // ws layout (f32): wd[15*68*68] | zT[68*B] | X[340*B]  (~27.1 MB total)
  float* wd = (float*)d_ws;
  float* zT = wd + R_ * NL * NN * NN;
  float* X  = zT + (size_t)LAT * B;

  const int nb = B / 64;                      // 256 batch-groups (chain)

  densify_k<<<R_ * NL, 128, 0, stream>>>(adj, gw, wd);
  ztr_k<<<B / 64, 256, 0, stream>>>(z, zT, B);
  chain_k<<<R_ * nb, 256, 0, stream>>>(zT, fc_w, fc_b, wd, gb, X, B, nb);
  outer_k<<<B / BBK2, 320, 0, stream>>>(X, out, B);
}

// Round 12
// 126.565 us; speedup vs baseline: 1.1954x; 1.1371x over previous
//
#include <hip/hip_runtime.h>
#include <math.h>

// Problem constants
#define R_ 5
#define NN 68        // N_NODES == LATENT
#define KK 32        // neighbors per node
#define NL 3         // GCN layers
#define LAT 68
#define NSL 17               // nodes per wave slice (4 waves x 17 = 68)
#define ROWQ (NN / 4)        // 17 float4 per node row
#define NF4 ((NN * NN) / 4)  // 1156 float4 per output row
#define BBK2 16              // batches per K2 block
#define LSTR 344             // LDS row stride (floats) for K2, 16B-aligned
#define NPREP (R_ * NL)      // 15 densify blocks inside prep_k

// ---------------- P: merged prep (densify + z-transpose) ----------------
// blocks [0,15): W'[m][n] = sum_{k: adj[n,k]==m} gw[n,k]
// blocks [15, 15+B/64): zT[l][b] transpose tile
__global__ __launch_bounds__(256) void prep_k(
    const float* __restrict__ z, const int* __restrict__ adj,
    const float* __restrict__ gw, float* __restrict__ wd,
    float* __restrict__ zT, int B) {
  const int t = threadIdx.x;
  if (blockIdx.x < NPREP) {
    const int rl = blockIdx.x;  // r*NL + l
    __shared__ float col[NN][NN + 4];
    for (int i = t; i < NN * (NN + 4); i += 256) (&col[0][0])[i] = 0.0f;
    __syncthreads();
    if (t < NN) {
      const int n = t;  // thread owns column n -> no races
      const int* ar = adj + n * KK;
      const float* wr = gw + ((size_t)rl * NN + n) * KK;
      for (int k = 0; k < KK; ++k) col[ar[k]][n] += wr[k];
    }
    __syncthreads();
    float* wout = wd + (size_t)rl * NN * NN;  // [m][n], n contiguous
    for (int i = t; i < NN * NN; i += 256) {
      const int m = i / NN, n = i - m * NN;
      wout[i] = col[m][n];
    }
  } else {
    const int b0 = (blockIdx.x - NPREP) * 64;
    __shared__ float zls[64][LAT + 1];  // +1: stride 69, conflict-free
    for (int idx = t; idx < 64 * ROWQ; idx += 256) {
      const int row = idx / ROWQ, q = idx - row * ROWQ;
      const float4 v =
          *reinterpret_cast<const float4*>(z + (size_t)(b0 + row) * LAT + 4 * q);
      zls[row][4 * q + 0] = v.x;
      zls[row][4 * q + 1] = v.y;
      zls[row][4 * q + 2] = v.z;
      zls[row][4 * q + 3] = v.w;
    }
    __syncthreads();
    for (int idx = t; idx < LAT * 64; idx += 256) {
      const int l = idx >> 6, bb = idx & 63;
      zT[(size_t)l * B + b0 + bb] = zls[bb][l];
    }
  }
}

// ---------------- K1: GEMM-chain, 4 waves x 17-node slices, chunked m -----
// v6 structure (scalar s_load weights, 20 waves/CU) with the m-loop split
// into 4 chunks of 17: the chunk's 17 xm values are hoisted into VGPRs
// (static-indexed) so the 289-fmac inner body waits only on the SMEM weight
// stream. Rationale: DS+SMEM share lgkmcnt and SMEM completes out-of-order,
// so v6's per-m ds_read/s_load interleave forced a full lgkmcnt(0) drain
// (~150 cyc) every 34 VALU cycles -> 66% stall (matches measured 2.9x floor).
// Chunking cuts drains from 68/stage to ~4/stage.
__global__ __launch_bounds__(256) void chain_k(
    const float* __restrict__ zT, const float* __restrict__ fc_w,
    const float* __restrict__ fc_b, const float* __restrict__ wd,
    const float* __restrict__ gb, float* __restrict__ X, int B, int nb) {
  const int t = threadIdx.x;
  const int lane = t & 63;
  const int w = __builtin_amdgcn_readfirstlane(t >> 6);
  const int n0 = w * NSL;  // first node of this wave's slice (wave-uniform)
  const int r = blockIdx.x / nb;
  const int b0 = (blockIdx.x - r * nb) * 64;

  __shared__ float xs[NN][64];  // 17.4 KB; z, then x, per stage

  for (int idx = t; idx < NN * 64; idx += 256) {
    const int m = idx >> 6;
    xs[m][idx & 63] = zT[(size_t)m * B + b0 + (idx & 63)];
  }
  __syncthreads();

  float acc[NSL];

#pragma unroll 1
  for (int stage = 0; stage < 1 + NL; ++stage) {
    const float* wb = (stage == 0) ? fc_w + (size_t)r * LAT * NN
                                   : wd + (size_t)(r * NL + stage - 1) * NN * NN;
    const float* bias = (stage == 0) ? fc_b + r * NN
                                     : gb + (size_t)(r * NL + stage - 1) * NN;
#pragma unroll
    for (int j = 0; j < NSL; ++j) acc[j] = bias[n0 + j];  // uniform -> s_load

#pragma unroll 1
    for (int mb = 0; mb < 4; ++mb) {  // 4 chunks of 17 rows
      float xmv[NSL];                 // statically indexed -> stays in VGPRs
#pragma unroll
      for (int k = 0; k < NSL; ++k) xmv[k] = xs[mb * NSL + k][lane];
      const float* wrb = wb + (size_t)(mb * NSL) * NN + n0;
#pragma unroll
      for (int k = 0; k < NSL; ++k) {
        const float* wr = wrb + (size_t)k * NN;  // wave-uniform -> s_load
#pragma unroll
        for (int j = 0; j < NSL; ++j) acc[j] = fmaf(xmv[k], wr[j], acc[j]);
      }
    }
    if (stage > 0) {
#pragma unroll
      for (int j = 0; j < NSL; ++j)
        acc[j] = 1.0f / (1.0f + __expf(-acc[j]));
    }
    if (stage < NL) {
      __syncthreads();  // everyone done READING xs for this stage
#pragma unroll
      for (int j = 0; j < NSL; ++j) xs[n0 + j][lane] = acc[j];
      __syncthreads();
    }
  }

  // ---- final X -> ws, layout [r*68+n][b]: coalesced 256B rows ----
  float* Xb = X + ((size_t)r * NN + n0) * B + b0 + lane;
#pragma unroll
  for (int j = 0; j < NSL; ++j) Xb[(size_t)j * B] = acc[j];
}

// ---------------- K2: outer product + store (flat, measured-best) ----------
// Exact revert to the v6 flat version (~73 us): consecutive lanes write
// consecutive f4 -> 1KB/instr fully-coalesced, full-line coverage.
__global__ __launch_bounds__(256) void outer_k(const float* __restrict__ X,
                                               float* __restrict__ out, int B) {
  const int t = threadIdx.x;
  const int b0 = blockIdx.x * BBK2;
  __shared__ float xls[BBK2 * LSTR];

  // stage X[rn][b0..b0+15] -> xls[bb][rn]; reads are exact 64B lines
  for (int idx = t; idx < R_ * NN * BBK2; idx += 256) {
    const int rn = idx >> 4, bb = idx & (BBK2 - 1);
    xls[bb * LSTR + rn] = X[(size_t)rn * B + b0 + bb];
  }
  __syncthreads();

  float4* ob = reinterpret_cast<float4*>(out) + (size_t)b0 * NF4;
  const int total = BBK2 * NF4;  // 18496
  for (int fg = t; fg < total; fg += 256) {
    const int bb = fg / NF4;
    const int f = fg - bb * NF4;
    const int i = f / ROWQ;
    const int q = f - i * ROWQ;
    const float* xb = &xls[bb * LSTR];
    float4 a = make_float4(0.f, 0.f, 0.f, 0.f);
#pragma unroll
    for (int r = 0; r < R_; ++r) {
      const float xi = xb[r * NN + i];
      const float4 xj = *reinterpret_cast<const float4*>(xb + r * NN + 4 * q);
      a.x = fmaf(xi, xj.x, a.x);
      a.y = fmaf(xi, xj.y, a.y);
      a.z = fmaf(xi, xj.z, a.z);
      a.w = fmaf(xi, xj.w, a.w);
    }
    ob[fg] = a;  // lanes consecutive -> perfectly coalesced
  }
}

extern "C" void kernel_launch(void* const* d_in, const int* in_sizes, int n_in,
                              void* d_out, int out_size, void* d_ws, size_t ws_size,
                              hipStream_t stream) {
  const float* z    = (const float*)d_in[0];  // (16384, 68)
  const int*   adj  = (const int*)  d_in[1];  // (68, 32)
  const float* fc_w = (const float*)d_in[2];  // (5, 68, 68)
  const float* fc_b = (const float*)d_in[3];  // (5, 68)
  const float* gw   = (const float*)d_in[4];  // (5, 3, 68, 32)
  const float* gb   = (const float*)d_in[5];  // (5, 3, 68)
  float* out = (float*)d_out;                 // (16384, 4624)

  const int B = in_sizes[0] / LAT;            // 16384
  // ws layout (f32): wd[15*68*68] | zT[68*B] | X[340*B]  (~27.1 MB total)
  float* wd = (float*)d_ws;
  float* zT = wd + R_ * NL * NN * NN;
  float* X  = zT + (size_t)LAT * B;

  const int nb = B / 64;                      // 256 batch-groups (chain)

  prep_k<<<NPREP + B / 64, 256, 0, stream>>>(z, adj, gw, wd, zT, B);
  chain_k<<<R_ * nb, 256, 0, stream>>>(zT, fc_w, fc_b, wd, gb, X, B, nb);
  outer_k<<<B / BBK2, 256, 0, stream>>>(X, out, B);
}